// Round 1
// 5708.558 us; speedup vs baseline: 1.0163x; 1.0163x over previous
//
#include <hip/hip_runtime.h>
#include <hip/hip_bf16.h>
#include <cstddef>

// ---------------------------------------------------------------------------
// AttentionLSTMDecoder on MI355X.  Round 3.
//  * Rounds 1-2: K/V folded into pos-affine scores, exp Taylor -> V-moment
//    ratio; Wo folded into W_ih0; one K=1088/1024 GEMM per layer per step.
//  * Round 3: the 100-step loop (300 dependent small launches, ~45us/step of
//    dispatch gap) becomes ONE persistent kernel with an in-kernel two-level
//    device-scope grid barrier.  Gate-GEMM and head/attention math unchanged
//    (s3 remapped 512->256 threads).  Fallback to multi-launch if the
//    occupancy query cannot prove 640-block co-residency.
// ---------------------------------------------------------------------------

typedef _Float16 hx8 __attribute__((ext_vector_type(8)));
typedef float fx4 __attribute__((ext_vector_type(4)));

#define NSEQ 640
#define TSTEPS 100
#define XC0 1088   // [x(576) | h0(512)]
#define XC1 1024   // [h0(512) | h1(512)]
#define NBLK 640   // persistent grid
#define BGROUPS 8
#define BGSIZE 80  // NBLK / BGROUPS

__device__ __forceinline__ float sigm(float x){ return 1.0f/(1.0f+__expf(-x)); }
__device__ __forceinline__ float tanh_(float x){
  x = fminf(fmaxf(x, -15.0f), 15.0f);
  float e = __expf(2.0f*x);
  return (e-1.0f)/(e+1.0f);
}
__device__ __forceinline__ float sel4(float a0,float a1,float a2,float a3,int h){
  float r = a0; r = (h==1)?a1:r; r = (h==2)?a2:r; r = (h==3)?a3:r; return r;
}

// ---------------- fold kernels (one-time) ----------------

__global__ void kF1(const float* __restrict__ Wq, const float* __restrict__ Wc,
                    const float* __restrict__ bc, const float* __restrict__ bq,
                    float* __restrict__ u){
  int r = blockIdx.x*256 + threadIdx.x; if (r >= 512) return;
  float s0=0.f, s1=0.f, s2=0.f;
  for (int k=0;k<512;k++){
    float wq = Wq[r*512+k];
    s0 += wq*Wc[k*512+0];
    s1 += wq*Wc[k*512+1];
    s2 += wq*bc[k];
  }
  u[r]=s0; u[512+r]=s1; u[1024+r]=s2+bq[r];
}

__global__ __launch_bounds__(512) void kF2a(const float* __restrict__ Wk,
                                            const float* __restrict__ u,
                                            float* __restrict__ z){
  int ih = blockIdx.x; int kk = threadIdx.x;
  int i = ih>>2, h = ih&3;
  float s = 0.f;
  for (int d=0; d<128; d++)
    s += Wk[(h*128+d)*512 + kk] * u[i*512 + h*128 + d];
  z[ih*512+kk] = s;
}

__global__ __launch_bounds__(512) void kF2b(const float* __restrict__ z,
                                            const float* __restrict__ Wc,
                                            const float* __restrict__ bc,
                                            const float* __restrict__ bk,
                                            const float* __restrict__ u,
                                            float* __restrict__ Y, float* __restrict__ cc){
  const float scale = 0.08838834764831845f; // 1/sqrt(128)
  int ih = blockIdx.x; int j = threadIdx.x;
  int i = ih>>2, h = ih&3;
  float s = 0.f;
  for (int kk=0;kk<512;kk++) s += z[ih*512+kk]*Wc[kk*512+j];
  Y[ih*512+j] = s*scale;
  if (j==0){
    float t=0.f;
    for (int kk=0;kk<512;kk++) t += z[ih*512+kk]*bc[kk];
    for (int d=0;d<128;d++) t += u[i*512+h*128+d]*bk[h*128+d];
    cc[ih] = t*scale;
  }
}

__global__ void kFbv(const float* __restrict__ Wv, const float* __restrict__ bc,
                     const float* __restrict__ bv, float* __restrict__ bv2){
  int r = blockIdx.x*256 + threadIdx.x; if (r >= 512) return;
  float s = bv[r];
  for (int k=0;k<512;k++) s += Wv[r*512+k]*bc[k];
  bv2[r]=s;
}

// fp32 tiled GEMM: C[M,N] = A[:, aoff:aoff+K] @ B (64x64 tiles)
__global__ __launch_bounds__(256) void kgemm(const float* __restrict__ A, int lda, int aoff,
                                             const float* __restrict__ B, int ldb,
                                             float* __restrict__ C, int ldc, int K){
  __shared__ float As[64][16];
  __shared__ float Bs[16][64];
  int tid = threadIdx.x; int tx = tid&15, ty = tid>>4;
  int bx = blockIdx.x, by = blockIdx.y;
  float acc[4][4];
#pragma unroll
  for (int i=0;i<4;i++)
#pragma unroll
    for (int j=0;j<4;j++) acc[i][j]=0.f;
  for (int kk=0; kk<K; kk+=16){
#pragma unroll
    for (int e=0;e<4;e++){
      int id = tid*4+e;
      int r = id>>4, c = id&15;
      As[r][c] = A[(size_t)(by*64+r)*lda + aoff + kk + c];
      int r2 = id>>6, c2 = id&63;
      Bs[r2][c2] = B[(size_t)(kk+r2)*ldb + bx*64 + c2];
    }
    __syncthreads();
#pragma unroll
    for (int k=0;k<16;k++){
      float bvv[4];
#pragma unroll
      for (int j=0;j<4;j++) bvv[j] = Bs[k][tx*4+j];
#pragma unroll
      for (int i=0;i<4;i++){
        float av = As[ty*4+i][k];
#pragma unroll
        for (int j=0;j<4;j++) acc[i][j] += av*bvv[j];
      }
    }
    __syncthreads();
  }
#pragma unroll
  for (int i=0;i<4;i++)
#pragma unroll
    for (int j=0;j<4;j++)
      C[(size_t)(by*64+ty*4+i)*ldc + bx*64+tx*4+j] = acc[i][j];
}

__global__ void ktransp(const float* __restrict__ A, float* __restrict__ AT){
  int idx = blockIdx.x*256 + threadIdx.x;
  int r = idx>>9, c = idx&511;
  AT[c*512 + r] = A[idx];
}

// Bcat0 [2048][1088] = [Wih0[:,0:36] | Wmix | 0pad(28) | Whh0]
__global__ void kbcat0(const float* __restrict__ Wih0, const float* __restrict__ Wmix,
                       const float* __restrict__ Whh0, _Float16* __restrict__ B){
  int r = blockIdx.x;
  for (int c = threadIdx.x; c < 1088; c += 256){
    float v;
    if (c < 36) v = Wih0[r*548 + c];
    else if (c < 548) v = Wmix[r*512 + (c-36)];
    else if (c < 576) v = 0.f;
    else v = Whh0[r*512 + (c-576)];
    B[(size_t)r*1088 + c] = (_Float16)v;
  }
}

// Bcat1 [2048][1024] = [Wih1 | Whh1]
__global__ void kbcat1(const float* __restrict__ Wih1, const float* __restrict__ Whh1,
                       _Float16* __restrict__ B){
  int r = blockIdx.x;
  for (int c = threadIdx.x; c < 1024; c += 256){
    float v = (c < 512) ? Wih1[r*512 + c] : Whh1[r*512 + (c-512)];
    B[(size_t)r*1024 + c] = (_Float16)v;
  }
}

__global__ void kcast(const float* __restrict__ s, _Float16* __restrict__ d, int n){
  int i = blockIdx.x*256 + threadIdx.x;
  if (i < n) d[i] = (_Float16)s[i];
}

// b0 = bih0+bhh0+Wih0[:,36:]@bo ; b1 = bih1+bhh1
__global__ void kbias(const float* __restrict__ Wih0, const float* __restrict__ bo,
                      const float* __restrict__ bih0, const float* __restrict__ bhh0,
                      const float* __restrict__ bih1, const float* __restrict__ bhh1,
                      float* __restrict__ b0, float* __restrict__ b1){
  int j = blockIdx.x*256 + threadIdx.x; if (j >= 2048) return;
  float s = bih0[j]+bhh0[j];
  for (int k=0;k<512;k++) s += Wih0[j*548+36+k]*bo[k];
  b0[j]=s; b1[j]=bih1[j]+bhh1[j];
}

// ---------------- moment precompute ----------------

__global__ __launch_bounds__(256) void kP1(const float* __restrict__ ctx,
                                           const float* __restrict__ Y,
                                           const float* __restrict__ cc,
                                           float* __restrict__ W6){
  __shared__ float Yl[6144];
  __shared__ float ccl[12];
  int tid = threadIdx.x; int n = blockIdx.x;
  for (int e = tid; e < 6144; e += 256) Yl[e] = Y[e];
  if (tid < 12) ccl[tid] = cc[tid];
  __syncthreads();
  int wave = tid >> 6, lane = tid & 63;
  for (int it = 0; it < 50; ++it){
    int s = it*4 + wave;
    const float* cp = ctx + ((size_t)n*200 + s)*512;
    float p[12];
#pragma unroll
    for (int i=0;i<12;i++) p[i]=0.f;
    for (int c8 = 0; c8 < 8; ++c8){
      int col = c8*64 + lane;
      float v = cp[col];
#pragma unroll
      for (int i=0;i<12;i++) p[i] += v * Yl[i*512+col];
    }
#pragma unroll
    for (int m = 32; m; m >>= 1){
#pragma unroll
      for (int i=0;i<12;i++) p[i] += __shfl_xor(p[i], m, 64);
    }
    if (lane < 4){
      int h = lane;
      float a  = sel4(p[0],p[1],p[2], p[3], h) + ccl[h];
      float b  = sel4(p[4],p[5],p[6], p[7], h) + ccl[4+h];
      float cp_= sel4(p[8],p[9],p[10],p[11],h) + ccl[8+h];
      float beta = __expf(cp_);
      size_t base = (size_t)(n*24 + h*6)*200 + s;
      W6[base + 0*200] = beta;
      W6[base + 1*200] = beta*a;
      W6[base + 2*200] = beta*b;
      W6[base + 3*200] = beta*a*a*0.5f;
      W6[base + 4*200] = beta*a*b;
      W6[base + 5*200] = beta*b*b*0.5f;
    }
  }
}

__global__ __launch_bounds__(256) void kP2(const float* __restrict__ ctx,
                                           const float* __restrict__ W6,
                                           float* __restrict__ F, float* __restrict__ S){
  __shared__ float w6[4800];
  int tid = threadIdx.x, n = blockIdx.x;
  for (int e = tid; e < 4800; e += 256) w6[e] = W6[(size_t)n*4800 + e];
  __syncthreads();
  float a0[24], a1[24];
#pragma unroll
  for (int r=0;r<24;r++){ a0[r]=0.f; a1[r]=0.f; }
  const float* cp = ctx + (size_t)n*200*512;
  for (int s=0;s<200;s++){
    float v0 = cp[s*512 + tid];
    float v1 = cp[s*512 + tid + 256];
#pragma unroll
    for (int r=0;r<24;r++){ float w = w6[r*200+s]; a0[r]+=w*v0; a1[r]+=w*v1; }
  }
#pragma unroll
  for (int r=0;r<24;r++){
    F[(size_t)(n*24+r)*512 + tid]       = a0[r];
    F[(size_t)(n*24+r)*512 + tid + 256] = a1[r];
  }
  if (tid < 24){
    float s=0.f;
    for (int ss=0; ss<200; ss++) s += w6[tid*200+ss];
    S[n*24+tid]=s;
  }
}

__global__ __launch_bounds__(128) void kP3(const float* __restrict__ F,
                                           const float* __restrict__ WcvT,
                                           float* __restrict__ M){
  __shared__ float Fl[3072];
  int tid = threadIdx.x; int b = blockIdx.x; int n = b>>2, h = b&3;
  for (int e = tid; e < 3072; e += 128) Fl[e] = F[(size_t)(n*24 + h*6)*512 + e];
  __syncthreads();
  float acc[6];
#pragma unroll
  for (int i=0;i<6;i++) acc[i]=0.f;
  for (int k=0;k<512;k++){
    float w = WcvT[k*512 + h*128 + tid];
#pragma unroll
    for (int i=0;i<6;i++) acc[i] += w * Fl[i*512+k];
  }
#pragma unroll
  for (int i=0;i<6;i++) M[(size_t)(n*24+h*6+i)*128 + tid] = acc[i];
}

// ---------------- state init ----------------

// fills both xcat buffers' constant regions + zeros, zeros both hcat, zeros c,
// zeros the grid-barrier counters (block 0)
__global__ __launch_bounds__(512) void kinit(const float* __restrict__ ball,
                    const int* __restrict__ roles, const float* __restrict__ remb,
                    _Float16* __restrict__ x0, _Float16* __restrict__ x1,
                    _Float16* __restrict__ hc0, _Float16* __restrict__ hc1,
                    float* __restrict__ c0, float* __restrict__ c1,
                    unsigned* __restrict__ bar){
  int n = blockIdx.x, tid = threadIdx.x;
  int b = n/10;
  int role = roles[n];
  for (int c = tid; c < XC0; c += 512){
    float v = 0.f;
    if (c>=2 && c<4)       v = ball[b*2 + (c-2)];
    else if (c>=4 && c<36) v = remb[role*32 + (c-4)];
    _Float16 hv = (_Float16)v;
    x0[(size_t)n*XC0+c] = hv;
    x1[(size_t)n*XC0+c] = hv;
  }
  for (int c = tid; c < XC1; c += 512){
    hc0[(size_t)n*XC1+c] = (_Float16)0.f;
    hc1[(size_t)n*XC1+c] = (_Float16)0.f;
  }
  for (int e = tid; e < 512; e += 512){
    c0[n*512+e]=0.f; c1[n*512+e]=0.f;
  }
  if (n == 0 && tid < 256) bar[tid] = 0u;
}

// attention (Taylor-moment) for t=0 into xcat buf0
__global__ __launch_bounds__(128) void katt0(const float* __restrict__ ipos,
                                             const float* __restrict__ M,
                                             const float* __restrict__ S,
                                             const float* __restrict__ bv2,
                                             _Float16* __restrict__ x){
  int n = blockIdx.x, tid = threadIdx.x;
  float p0 = ipos[n*2], p1 = ipos[n*2+1];
  if (tid==0){ x[(size_t)n*XC0]=(_Float16)p0; x[(size_t)n*XC0+1]=(_Float16)p1; }
  float fa=p0*p0, fb=p0*p1, fc=p1*p1;
  for (int hd = tid; hd < 512; hd += 128){
    int h = hd>>7;
    int sb = n*24 + h*6;
    float den = S[sb] + p0*S[sb+1] + p1*S[sb+2] + fa*S[sb+3] + fb*S[sb+4] + fc*S[sb+5];
    const float* mp = M + (size_t)sb*128 + (hd&127);
    float num = mp[0] + p0*mp[128] + p1*mp[256] + fa*mp[384] + fb*mp[512] + fc*mp[640];
    x[(size_t)n*XC0 + 36 + hd] = (_Float16)(num/den + bv2[hd]);
  }
}

// ---------------- per-step bodies (shared by fallback + persistent) ----------

// One layer's full gate GEMM (K = lda cat width) + fused LSTM.
// 640 tasks = 20 mblk (32 rows) x 32 jb (16 cols/gate). 4 waves, 1 gate each.
// LDS double-buffered K=64 chunks; sbase = 2*6144 halfs, eps = [4][32][16] f.
__device__ __forceinline__ void gates_body(
    const _Float16* __restrict__ A, int lda, int nc,
    const _Float16* __restrict__ B,
    const float* __restrict__ bias, float* __restrict__ cst,
    _Float16* __restrict__ h1p, int ldh1, int co1,
    _Float16* __restrict__ h2p, int ldh2, int co2,
    int bx, _Float16* sbase, float (*eps)[32][16]){
  int tid = threadIdx.x, w = tid>>6, lane = tid&63;
  int lr = lane&15, lq = lane>>4;
  int mblk = bx>>5, jb = bx&31;
  int m0 = mblk*32, j0 = jb*16;
  int li = lane>>3, lc = lane&7;
  const _Float16* gA  = A + (size_t)(m0 + w*8 + li)*lda + lc*8;
  const _Float16* gB0 = B + (size_t)(w*512 + j0 + li)*lda + lc*8;
  const _Float16* gB1 = B + (size_t)(w*512 + j0 + 8 + li)*lda + lc*8;
  int sA  = (w*8 + li)*64 + lc*8;
  int sB0 = 2048 + (w*16 + li)*64 + lc*8;
  int sB1 = sB0 + 8*64;
  int fA0 = lr*64 + lq*8;
  int fA1 = (16+lr)*64 + lq*8;
  int fB  = 2048 + (w*16 + lr)*64 + lq*8;
  hx8 rA  = *(const hx8*)(gA);
  hx8 rB0 = *(const hx8*)(gB0);
  hx8 rB1 = *(const hx8*)(gB1);
  fx4 ac0={0.f,0.f,0.f,0.f}, ac1={0.f,0.f,0.f,0.f};
  for (int c=0; c<nc; ++c){
    _Float16* sb = sbase + (c&1)*6144;
    *(hx8*)(sb + sA)  = rA;
    *(hx8*)(sb + sB0) = rB0;
    *(hx8*)(sb + sB1) = rB1;
    __syncthreads();
    if (c+1 < nc){
      int k = (c+1)*64;
      rA  = *(const hx8*)(gA  + k);
      rB0 = *(const hx8*)(gB0 + k);
      rB1 = *(const hx8*)(gB1 + k);
    }
    hx8 b0 = *(const hx8*)(sb + fB);
    hx8 a0 = *(const hx8*)(sb + fA0);
    hx8 a1 = *(const hx8*)(sb + fA1);
    ac0 = __builtin_amdgcn_mfma_f32_16x16x32_f16(a0, b0, ac0, 0,0,0);
    ac1 = __builtin_amdgcn_mfma_f32_16x16x32_f16(a1, b0, ac1, 0,0,0);
    hx8 b1  = *(const hx8*)(sb + fB  + 32);
    hx8 a0b = *(const hx8*)(sb + fA0 + 32);
    hx8 a1b = *(const hx8*)(sb + fA1 + 32);
    ac0 = __builtin_amdgcn_mfma_f32_16x16x32_f16(a0b, b1, ac0, 0,0,0);
    ac1 = __builtin_amdgcn_mfma_f32_16x16x32_f16(a1b, b1, ac1, 0,0,0);
  }
#pragma unroll
  for (int r=0;r<4;r++){
    eps[w][lq*4+r][lr]    = ac0[r];
    eps[w][16+lq*4+r][lr] = ac1[r];
  }
  __syncthreads();
#pragma unroll
  for (int e=0;e<2;e++){
    int idx = e*256 + tid;
    int ml = idx>>4, j = idx&15;
    float gi = eps[0][ml][j] + bias[       j0+j];
    float gf = eps[1][ml][j] + bias[ 512 + j0+j];
    float gg = eps[2][ml][j] + bias[1024 + j0+j];
    float go = eps[3][ml][j] + bias[1536 + j0+j];
    int ci = (m0+ml)*512 + j0 + j;
    float c_ = cst[ci];
    float cn = sigm(gf)*c_ + sigm(gi)*tanh_(gg);
    float hn = sigm(go)*tanh_(cn);
    cst[ci] = cn;
    _Float16 hh = (_Float16)hn;
    h1p[(size_t)(m0+ml)*ldh1 + co1 + j0 + j] = hh;
    if (h2p) h2p[(size_t)(m0+ml)*ldh2 + co2 + j0 + j] = hh;
  }
}

// fallback wrapper (identical behavior to round-2 kgates)
__global__ __launch_bounds__(256) void kgates(
    const _Float16* __restrict__ A, int lda, int nc,
    const _Float16* __restrict__ B,
    const float* __restrict__ bias, float* __restrict__ cst,
    _Float16* __restrict__ h1p, int ldh1, int co1,
    _Float16* __restrict__ h2p, int ldh2, int co2){
  __shared__ __align__(16) char smem[32768];
  gates_body(A, lda, nc, B, bias, cst, h1p, ldh1, co1, h2p, ldh2, co2,
             blockIdx.x, (_Float16*)smem, (float(*)[32][16])(smem + 24576));
}

// head + next-step attention, 256 threads, 16 seqs per call (n0 = base seq).
// Remap of round-2 ks3 (512 thr): wave w covers hid cols [w*64,(w+1)*64).
__device__ __forceinline__ void s3_body(const _Float16* __restrict__ h1, int ldh,
    const _Float16* __restrict__ Wf1, const float* __restrict__ bf1,
    const float* __restrict__ Wf2, const float* __restrict__ bf2,
    const float* __restrict__ M, const float* __restrict__ S,
    const float* __restrict__ bv2, _Float16* __restrict__ xn,
    float* __restrict__ out, int t, int n0,
    float (*hid)[264], float (*posL)[2], float (*denL)[4]){
  int tid = threadIdx.x, w = tid>>6, lane = tid&63;
  int lr = lane&15, lq = lane>>4;
  fx4 acc[4];
#pragma unroll
  for (int c=0;c<4;c++) acc[c] = (fx4){0.f,0.f,0.f,0.f};
  {
    const _Float16* ap = h1 + (size_t)(n0+lr)*ldh + lq*8;
    for (int ks=0; ks<16; ks++){
      hx8 a = *(const hx8*)(ap + ks*32);
#pragma unroll
      for (int c=0;c<4;c++){
        const _Float16* bp = Wf1 + (size_t)(w*64 + c*16 + lr)*512 + ks*32 + lq*8;
        acc[c] = __builtin_amdgcn_mfma_f32_16x16x32_f16(a, *(const hx8*)bp, acc[c], 0,0,0);
      }
    }
  }
#pragma unroll
  for (int c=0;c<4;c++)
#pragma unroll
    for (int r=0;r<4;r++){
      int col = w*64 + c*16 + lr;
      hid[lq*4+r][col] = fmaxf(acc[c][r] + bf1[col], 0.f);
    }
  __syncthreads();
  {
    int nn = tid>>4, o = (tid>>3)&1, sub = tid&7;
    float s = 0.f;
#pragma unroll
    for (int k2=0;k2<32;k2++) s += hid[nn][k2*8 + sub] * Wf2[o*256 + k2*8 + sub];
    s += __shfl_xor(s, 1, 64);
    s += __shfl_xor(s, 2, 64);
    s += __shfl_xor(s, 4, 64);
    if (sub==0){
      s += bf2[o];
      out[((size_t)(n0+nn)*TSTEPS + t)*2 + o] = s;
      posL[nn][o] = s;
      xn[(size_t)(n0+nn)*XC0 + o] = (_Float16)s;
    }
  }
  __syncthreads();
  if (tid < 64){
    int nn = tid>>2, h = tid&3;
    float p0 = posL[nn][0], p1 = posL[nn][1];
    int sb = (n0+nn)*24 + h*6;
    float den = S[sb] + p0*S[sb+1] + p1*S[sb+2] + p0*p0*S[sb+3] + p0*p1*S[sb+4] + p1*p1*S[sb+5];
    denL[nn][h] = 1.0f/den;
  }
  __syncthreads();
#pragma unroll
  for (int half=0; half<2; half++){
    int hd = half*256 + tid;
    int h = hd>>7, d = hd&127;
    for (int nn=0; nn<16; nn++){
      float p0 = posL[nn][0], p1 = posL[nn][1];
      float fa = p0*p0, fb = p0*p1, fc = p1*p1;
      const float* mp = M + (size_t)((n0+nn)*24 + h*6)*128 + d;
      float num = mp[0] + p0*mp[128] + p1*mp[256] + fa*mp[384] + fb*mp[512] + fc*mp[640];
      xn[(size_t)(n0+nn)*XC0 + 36 + hd] = (_Float16)(num*denL[nn][h] + bv2[hd]);
    }
  }
}

// fallback wrapper
__global__ __launch_bounds__(256) void ks3b(const _Float16* __restrict__ h1, int ldh,
    const _Float16* __restrict__ Wf1, const float* __restrict__ bf1,
    const float* __restrict__ Wf2, const float* __restrict__ bf2,
    const float* __restrict__ M, const float* __restrict__ S,
    const float* __restrict__ bv2, _Float16* __restrict__ xn,
    float* __restrict__ out, int t){
  __shared__ float hid[16][264];
  __shared__ float posL[16][2];
  __shared__ float denL[16][4];
  s3_body(h1, ldh, Wf1, bf1, Wf2, bf2, M, S, bv2, xn, out, t,
          blockIdx.x*16, hid, posL, denL);
}

// ---------------- persistent loop kernel ----------------

// Two-level grid barrier.  bar layout (u32): [g*16] group counters (g<8,
// 64B apart), [128] global counter, [144] generation.  Every arrival does an
// ACQ_REL agent-scope RMW => its XCD L2 is written back (release) and its
// CU L1/XCD L2 invalidated (acquire) -- correct under XCD non-coherence;
// the last arriver per CU/XCD performs the flush that matters.
__device__ __forceinline__ void gbar(unsigned* bar, int bid){
  __syncthreads();
  if (threadIdx.x == 0){
    unsigned* cg  = bar + (bid & (BGROUPS-1))*16;
    unsigned* gc  = bar + 128;
    unsigned* gen = bar + 144;
    unsigned g = __hip_atomic_load(gen, __ATOMIC_RELAXED, __HIP_MEMORY_SCOPE_AGENT);
    bool rel = false;
    unsigned o = __hip_atomic_fetch_add(cg, 1u, __ATOMIC_ACQ_REL, __HIP_MEMORY_SCOPE_AGENT);
    if (o == (unsigned)(BGSIZE-1)){
      __hip_atomic_store(cg, 0u, __ATOMIC_RELAXED, __HIP_MEMORY_SCOPE_AGENT);
      unsigned o2 = __hip_atomic_fetch_add(gc, 1u, __ATOMIC_ACQ_REL, __HIP_MEMORY_SCOPE_AGENT);
      if (o2 == (unsigned)(BGROUPS-1)){
        __hip_atomic_store(gc, 0u, __ATOMIC_RELAXED, __HIP_MEMORY_SCOPE_AGENT);
        __hip_atomic_store(gen, g + 1u, __ATOMIC_RELEASE, __HIP_MEMORY_SCOPE_AGENT);
        rel = true;
      }
    }
    if (!rel){
      while (__hip_atomic_load(gen, __ATOMIC_RELAXED, __HIP_MEMORY_SCOPE_AGENT) == g)
        __builtin_amdgcn_s_sleep(1);
      (void)__hip_atomic_load(gen, __ATOMIC_ACQUIRE, __HIP_MEMORY_SCOPE_AGENT);
    }
  }
  __syncthreads();
}

struct LoopArgs {
  const _Float16* B0; const _Float16* B1;
  const float* b0; const float* b1;
  float* c0; float* c1;
  _Float16* x0; _Float16* x1; _Float16* h0; _Float16* h1;
  const _Float16* Wf1; const float* bf1; const float* Wf2; const float* bf2;
  const float* M; const float* S; const float* bv2;
  float* out; unsigned* bar;
};

// 640 blocks x 256 thr, 32KB LDS/block (5 blocks/CU by LDS), min 3 waves/EU
// (VGPR <= 170) => >= 3 blocks/CU co-resident => 768 >= 640.  LDS is a union:
// gates phase uses [sbuf 24576 | eps 8192]; s3 phase overlays hid/posL/denL.
__global__ __launch_bounds__(256, 3) void kloop(LoopArgs a){
  __shared__ __align__(16) char smem[32768];
  _Float16* sbase = (_Float16*)smem;
  float (*eps)[32][16] = (float(*)[32][16])(smem + 24576);
  float (*hid)[264] = (float(*)[264])smem;
  float (*posL)[2] = (float(*)[2])(smem + 16896);
  float (*denL)[4] = (float(*)[4])(smem + 17024);
  int bid = blockIdx.x;
  for (int t = 0; t < TSTEPS; ++t){
    _Float16* xin = (t&1) ? a.x1 : a.x0;
    _Float16* xnx = (t&1) ? a.x0 : a.x1;
    _Float16* hin = (t&1) ? a.h1 : a.h0;
    _Float16* hnx = (t&1) ? a.h0 : a.h1;
    // layer 0: A=[x|h0] (K=1088) -> h0_t into hin[.,0:512] and xnx[.,576:1088]
    gates_body(xin, XC0, 17, a.B0, a.b0, a.c0, hin, XC1, 0, xnx, XC0, 576,
               bid, sbase, eps);
    gbar(a.bar, bid);
    // layer 1: A=[h0|h1] (K=1024) -> h1_t into hnx[.,512:1024]
    gates_body(hin, XC1, 16, a.B1, a.b1, a.c1, hnx, XC1, 512,
               (_Float16*)0, 0, 0, bid, sbase, eps);
    gbar(a.bar, bid);
    // head + attention for next x -> xnx[.,0:2], xnx[.,36:548]
    if (bid < 40)
      s3_body(hnx + 512, XC1, a.Wf1, a.bf1, a.Wf2, a.bf2, a.M, a.S, a.bv2,
              xnx, a.out, t, bid*16, hid, posL, denL);
    gbar(a.bar, bid);
  }
}

// ---------------------------------------------------------------------------

extern "C" void kernel_launch(void* const* d_in, const int* in_sizes, int n_in,
                              void* d_out, int out_size, void* d_ws, size_t ws_size,
                              hipStream_t stream) {
  const float* ctx   = (const float*)d_in[0];
  const float* ipos  = (const float*)d_in[1];
  const float* ball  = (const float*)d_in[2];
  const int*   roles = (const int*)  d_in[3];
  const float* remb  = (const float*)d_in[5];
  const float* Wc    = (const float*)d_in[6];
  const float* bc    = (const float*)d_in[7];
  const float* Wq    = (const float*)d_in[8];
  const float* bq    = (const float*)d_in[9];
  const float* Wk    = (const float*)d_in[10];
  const float* bk    = (const float*)d_in[11];
  const float* Wv    = (const float*)d_in[12];
  const float* bv    = (const float*)d_in[13];
  const float* Wo    = (const float*)d_in[14];
  const float* bo    = (const float*)d_in[15];
  const float* Wih0  = (const float*)d_in[16];
  const float* Whh0  = (const float*)d_in[17];
  const float* bih0  = (const float*)d_in[18];
  const float* bhh0  = (const float*)d_in[19];
  const float* Wih1  = (const float*)d_in[20];
  const float* Whh1  = (const float*)d_in[21];
  const float* bih1  = (const float*)d_in[22];
  const float* bhh1  = (const float*)d_in[23];
  const float* Wf1   = (const float*)d_in[24];
  const float* bf1   = (const float*)d_in[25];
  const float* Wf2   = (const float*)d_in[26];
  const float* bf2   = (const float*)d_in[27];
  float* out = (float*)d_out;

  char* w = (char*)d_ws;
  auto alloc = [&](size_t bytes){ void* p = (void*)w; w += (bytes + 255) & ~(size_t)255; return p; };
  float* fY    = (float*)alloc(12*512*4);
  float* fcc   = (float*)alloc(12*4);
  float* fu    = (float*)alloc(3*512*4);
  float* fz    = (float*)alloc(12*512*4);
  float* fbv2  = (float*)alloc(512*4);
  float* fWcv  = (float*)alloc((size_t)512*512*4);
  float* fWcvT = (float*)alloc((size_t)512*512*4);
  float* fWmix = (float*)alloc((size_t)2048*512*4);
  _Float16* hB0  = (_Float16*)alloc((size_t)2048*XC0*2);
  _Float16* hB1  = (_Float16*)alloc((size_t)2048*XC1*2);
  _Float16* hWf1 = (_Float16*)alloc((size_t)256*512*2);
  float* fb0 = (float*)alloc(2048*4);
  float* fb1 = (float*)alloc(2048*4);
  float* fW6 = (float*)alloc((size_t)NSEQ*24*200*4);
  float* fS  = (float*)alloc((size_t)NSEQ*24*4);
  float* fF  = (float*)alloc((size_t)NSEQ*24*512*4);
  float* fM  = (float*)alloc((size_t)NSEQ*24*128*4);
  _Float16* xc0 = (_Float16*)alloc((size_t)NSEQ*XC0*2);
  _Float16* xc1 = (_Float16*)alloc((size_t)NSEQ*XC0*2);
  _Float16* hc0 = (_Float16*)alloc((size_t)NSEQ*XC1*2);
  _Float16* hc1 = (_Float16*)alloc((size_t)NSEQ*XC1*2);
  float* fc0 = (float*)alloc((size_t)NSEQ*512*4);
  float* fc1 = (float*)alloc((size_t)NSEQ*512*4);
  unsigned* bar = (unsigned*)alloc(1024);

  // ---- folds ----
  kF1 <<<2,  256, 0, stream>>>(Wq, Wc, bc, bq, fu);
  kF2a<<<12, 512, 0, stream>>>(Wk, fu, fz);
  kF2b<<<12, 512, 0, stream>>>(fz, Wc, bc, bk, fu, fY, fcc);
  kFbv<<<2,  256, 0, stream>>>(Wv, bc, bv, fbv2);
  kgemm<<<dim3(8,8),  256, 0, stream>>>(Wv,   512, 0,  Wc, 512, fWcv,  512, 512);
  ktransp<<<1024, 256, 0, stream>>>(fWcv, fWcvT);
  kgemm<<<dim3(8,32), 256, 0, stream>>>(Wih0, 548, 36, Wo, 512, fWmix, 512, 512);
  kbcat0<<<2048, 256, 0, stream>>>(Wih0, fWmix, Whh0, hB0);
  kbcat1<<<2048, 256, 0, stream>>>(Wih1, Whh1, hB1);
  kcast<<<512,  256, 0, stream>>>(Wf1, hWf1, 256*512);
  kbias<<<8, 256, 0, stream>>>(Wih0, bo, bih0, bhh0, bih1, bhh1, fb0, fb1);

  // ---- moments ----
  kP1<<<NSEQ, 256, 0, stream>>>(ctx, fY, fcc, fW6);
  kP2<<<NSEQ, 256, 0, stream>>>(ctx, fW6, fF, fS);
  kP3<<<NSEQ*4, 128, 0, stream>>>(fF, fWcvT, fM);

  // ---- state init ----
  kinit<<<NSEQ, 512, 0, stream>>>(ball, roles, remb, xc0, xc1, hc0, hc1, fc0, fc1, bar);
  katt0<<<NSEQ, 128, 0, stream>>>(ipos, fM, fS, fbv2, xc0);

  // ---- recurrent loop: persistent kernel if co-residency is provable ----
  int maxb = 0;
  hipError_t qe = hipOccupancyMaxActiveBlocksPerMultiprocessor(
      &maxb, reinterpret_cast<const void*>(kloop), 256, 0);
  if (qe == hipSuccess && maxb >= 3){
    LoopArgs la;
    la.B0 = hB0; la.B1 = hB1; la.b0 = fb0; la.b1 = fb1;
    la.c0 = fc0; la.c1 = fc1;
    la.x0 = xc0; la.x1 = xc1; la.h0 = hc0; la.h1 = hc1;
    la.Wf1 = hWf1; la.bf1 = bf1; la.Wf2 = Wf2; la.bf2 = bf2;
    la.M = fM; la.S = fS; la.bv2 = fbv2; la.out = out; la.bar = bar;
    kloop<<<NBLK, 256, 0, stream>>>(la);
  } else {
    for (int t = 0; t < TSTEPS; ++t){
      _Float16* xin  = (t&1) ? xc1 : xc0;
      _Float16* xnx  = (t&1) ? xc0 : xc1;
      _Float16* hin  = (t&1) ? hc1 : hc0;
      _Float16* hnx  = (t&1) ? hc0 : hc1;
      kgates<<<640, 256, 0, stream>>>(xin, XC0, 17, hB0, fb0, fc0,
                                      hin, XC1, 0, xnx, XC0, 576);
      kgates<<<640, 256, 0, stream>>>(hin, XC1, 16, hB1, fb1, fc1,
                                      hnx, XC1, 512, (_Float16*)nullptr, 0, 0);
      ks3b<<<40, 256, 0, stream>>>(hnx + 512, XC1, hWf1, bf1, Wf2, bf2,
                                   fM, fS, fbv2, xnx, out, t);
    }
  }
}

// Round 2
// 4809.752 us; speedup vs baseline: 1.2063x; 1.1869x over previous
//
#include <hip/hip_runtime.h>
#include <hip/hip_bf16.h>
#include <cstddef>

// ---------------------------------------------------------------------------
// AttentionLSTMDecoder on MI355X.  Round 4.
//  * Rounds 1-2: K/V folded into pos-affine scores, exp Taylor -> V-moment
//    ratio; Wo folded into W_ih0; one K=1088/1024 GEMM per layer per step.
//  * Round 3: persistent kernel + grid barrier (removed 300 launches).
//  * Round 4 (this): rocprof showed SQ_LDS_BANK_CONFLICT=6.2e8 (16-way
//    conflicts on every gate-GEMM ds_read_b128: 128B row stride) and a
//    barrier costing ~7us (80 serialized same-line RMWs per group).
//    Fix 1: XOR-swizzle LDS tiles (slot ^= row&7) on BOTH write and read.
//    Fix 2: flag-array + master-scan barrier (1 store arrival, block 0
//    scans 640 flags with 256 threads, monotone generation values).
// ---------------------------------------------------------------------------

typedef _Float16 hx8 __attribute__((ext_vector_type(8)));
typedef float fx4 __attribute__((ext_vector_type(4)));

#define NSEQ 640
#define TSTEPS 100
#define XC0 1088   // [x(576) | h0(512)]
#define XC1 1024   // [h0(512) | h1(512)]
#define NBLK 640   // persistent grid
#define FL 32      // u32 stride per barrier flag line (128B)

__device__ __forceinline__ float sigm(float x){ return 1.0f/(1.0f+__expf(-x)); }
__device__ __forceinline__ float tanh_(float x){
  x = fminf(fmaxf(x, -15.0f), 15.0f);
  float e = __expf(2.0f*x);
  return (e-1.0f)/(e+1.0f);
}
__device__ __forceinline__ float sel4(float a0,float a1,float a2,float a3,int h){
  float r = a0; r = (h==1)?a1:r; r = (h==2)?a2:r; r = (h==3)?a3:r; return r;
}

// ---------------- fold kernels (one-time) ----------------

__global__ void kF1(const float* __restrict__ Wq, const float* __restrict__ Wc,
                    const float* __restrict__ bc, const float* __restrict__ bq,
                    float* __restrict__ u){
  int r = blockIdx.x*256 + threadIdx.x; if (r >= 512) return;
  float s0=0.f, s1=0.f, s2=0.f;
  for (int k=0;k<512;k++){
    float wq = Wq[r*512+k];
    s0 += wq*Wc[k*512+0];
    s1 += wq*Wc[k*512+1];
    s2 += wq*bc[k];
  }
  u[r]=s0; u[512+r]=s1; u[1024+r]=s2+bq[r];
}

__global__ __launch_bounds__(512) void kF2a(const float* __restrict__ Wk,
                                            const float* __restrict__ u,
                                            float* __restrict__ z){
  int ih = blockIdx.x; int kk = threadIdx.x;
  int i = ih>>2, h = ih&3;
  float s = 0.f;
  for (int d=0; d<128; d++)
    s += Wk[(h*128+d)*512 + kk] * u[i*512 + h*128 + d];
  z[ih*512+kk] = s;
}

__global__ __launch_bounds__(512) void kF2b(const float* __restrict__ z,
                                            const float* __restrict__ Wc,
                                            const float* __restrict__ bc,
                                            const float* __restrict__ bk,
                                            const float* __restrict__ u,
                                            float* __restrict__ Y, float* __restrict__ cc){
  const float scale = 0.08838834764831845f; // 1/sqrt(128)
  int ih = blockIdx.x; int j = threadIdx.x;
  int i = ih>>2, h = ih&3;
  float s = 0.f;
  for (int kk=0;kk<512;kk++) s += z[ih*512+kk]*Wc[kk*512+j];
  Y[ih*512+j] = s*scale;
  if (j==0){
    float t=0.f;
    for (int kk=0;kk<512;kk++) t += z[ih*512+kk]*bc[kk];
    for (int d=0;d<128;d++) t += u[i*512+h*128+d]*bk[h*128+d];
    cc[ih] = t*scale;
  }
}

__global__ void kFbv(const float* __restrict__ Wv, const float* __restrict__ bc,
                     const float* __restrict__ bv, float* __restrict__ bv2){
  int r = blockIdx.x*256 + threadIdx.x; if (r >= 512) return;
  float s = bv[r];
  for (int k=0;k<512;k++) s += Wv[r*512+k]*bc[k];
  bv2[r]=s;
}

// fp32 tiled GEMM: C[M,N] = A[:, aoff:aoff+K] @ B (64x64 tiles)
__global__ __launch_bounds__(256) void kgemm(const float* __restrict__ A, int lda, int aoff,
                                             const float* __restrict__ B, int ldb,
                                             float* __restrict__ C, int ldc, int K){
  __shared__ float As[64][16];
  __shared__ float Bs[16][64];
  int tid = threadIdx.x; int tx = tid&15, ty = tid>>4;
  int bx = blockIdx.x, by = blockIdx.y;
  float acc[4][4];
#pragma unroll
  for (int i=0;i<4;i++)
#pragma unroll
    for (int j=0;j<4;j++) acc[i][j]=0.f;
  for (int kk=0; kk<K; kk+=16){
#pragma unroll
    for (int e=0;e<4;e++){
      int id = tid*4+e;
      int r = id>>4, c = id&15;
      As[r][c] = A[(size_t)(by*64+r)*lda + aoff + kk + c];
      int r2 = id>>6, c2 = id&63;
      Bs[r2][c2] = B[(size_t)(kk+r2)*ldb + bx*64 + c2];
    }
    __syncthreads();
#pragma unroll
    for (int k=0;k<16;k++){
      float bvv[4];
#pragma unroll
      for (int j=0;j<4;j++) bvv[j] = Bs[k][tx*4+j];
#pragma unroll
      for (int i=0;i<4;i++){
        float av = As[ty*4+i][k];
#pragma unroll
        for (int j=0;j<4;j++) acc[i][j] += av*bvv[j];
      }
    }
    __syncthreads();
  }
#pragma unroll
  for (int i=0;i<4;i++)
#pragma unroll
    for (int j=0;j<4;j++)
      C[(size_t)(by*64+ty*4+i)*ldc + bx*64+tx*4+j] = acc[i][j];
}

__global__ void ktransp(const float* __restrict__ A, float* __restrict__ AT){
  int idx = blockIdx.x*256 + threadIdx.x;
  int r = idx>>9, c = idx&511;
  AT[c*512 + r] = A[idx];
}

// Bcat0 [2048][1088] = [Wih0[:,0:36] | Wmix | 0pad(28) | Whh0]
__global__ void kbcat0(const float* __restrict__ Wih0, const float* __restrict__ Wmix,
                       const float* __restrict__ Whh0, _Float16* __restrict__ B){
  int r = blockIdx.x;
  for (int c = threadIdx.x; c < 1088; c += 256){
    float v;
    if (c < 36) v = Wih0[r*548 + c];
    else if (c < 548) v = Wmix[r*512 + (c-36)];
    else if (c < 576) v = 0.f;
    else v = Whh0[r*512 + (c-576)];
    B[(size_t)r*1088 + c] = (_Float16)v;
  }
}

// Bcat1 [2048][1024] = [Wih1 | Whh1]
__global__ void kbcat1(const float* __restrict__ Wih1, const float* __restrict__ Whh1,
                       _Float16* __restrict__ B){
  int r = blockIdx.x;
  for (int c = threadIdx.x; c < 1024; c += 256){
    float v = (c < 512) ? Wih1[r*512 + c] : Whh1[r*512 + (c-512)];
    B[(size_t)r*1024 + c] = (_Float16)v;
  }
}

__global__ void kcast(const float* __restrict__ s, _Float16* __restrict__ d, int n){
  int i = blockIdx.x*256 + threadIdx.x;
  if (i < n) d[i] = (_Float16)s[i];
}

// b0 = bih0+bhh0+Wih0[:,36:]@bo ; b1 = bih1+bhh1
__global__ void kbias(const float* __restrict__ Wih0, const float* __restrict__ bo,
                      const float* __restrict__ bih0, const float* __restrict__ bhh0,
                      const float* __restrict__ bih1, const float* __restrict__ bhh1,
                      float* __restrict__ b0, float* __restrict__ b1){
  int j = blockIdx.x*256 + threadIdx.x; if (j >= 2048) return;
  float s = bih0[j]+bhh0[j];
  for (int k=0;k<512;k++) s += Wih0[j*548+36+k]*bo[k];
  b0[j]=s; b1[j]=bih1[j]+bhh1[j];
}

// ---------------- moment precompute ----------------

__global__ __launch_bounds__(256) void kP1(const float* __restrict__ ctx,
                                           const float* __restrict__ Y,
                                           const float* __restrict__ cc,
                                           float* __restrict__ W6){
  __shared__ float Yl[6144];
  __shared__ float ccl[12];
  int tid = threadIdx.x; int n = blockIdx.x;
  for (int e = tid; e < 6144; e += 256) Yl[e] = Y[e];
  if (tid < 12) ccl[tid] = cc[tid];
  __syncthreads();
  int wave = tid >> 6, lane = tid & 63;
  for (int it = 0; it < 50; ++it){
    int s = it*4 + wave;
    const float* cp = ctx + ((size_t)n*200 + s)*512;
    float p[12];
#pragma unroll
    for (int i=0;i<12;i++) p[i]=0.f;
    for (int c8 = 0; c8 < 8; ++c8){
      int col = c8*64 + lane;
      float v = cp[col];
#pragma unroll
      for (int i=0;i<12;i++) p[i] += v * Yl[i*512+col];
    }
#pragma unroll
    for (int m = 32; m; m >>= 1){
#pragma unroll
      for (int i=0;i<12;i++) p[i] += __shfl_xor(p[i], m, 64);
    }
    if (lane < 4){
      int h = lane;
      float a  = sel4(p[0],p[1],p[2], p[3], h) + ccl[h];
      float b  = sel4(p[4],p[5],p[6], p[7], h) + ccl[4+h];
      float cp_= sel4(p[8],p[9],p[10],p[11],h) + ccl[8+h];
      float beta = __expf(cp_);
      size_t base = (size_t)(n*24 + h*6)*200 + s;
      W6[base + 0*200] = beta;
      W6[base + 1*200] = beta*a;
      W6[base + 2*200] = beta*b;
      W6[base + 3*200] = beta*a*a*0.5f;
      W6[base + 4*200] = beta*a*b;
      W6[base + 5*200] = beta*b*b*0.5f;
    }
  }
}

__global__ __launch_bounds__(256) void kP2(const float* __restrict__ ctx,
                                           const float* __restrict__ W6,
                                           float* __restrict__ F, float* __restrict__ S){
  __shared__ float w6[4800];
  int tid = threadIdx.x, n = blockIdx.x;
  for (int e = tid; e < 4800; e += 256) w6[e] = W6[(size_t)n*4800 + e];
  __syncthreads();
  float a0[24], a1[24];
#pragma unroll
  for (int r=0;r<24;r++){ a0[r]=0.f; a1[r]=0.f; }
  const float* cp = ctx + (size_t)n*200*512;
  for (int s=0;s<200;s++){
    float v0 = cp[s*512 + tid];
    float v1 = cp[s*512 + tid + 256];
#pragma unroll
    for (int r=0;r<24;r++){ float w = w6[r*200+s]; a0[r]+=w*v0; a1[r]+=w*v1; }
  }
#pragma unroll
  for (int r=0;r<24;r++){
    F[(size_t)(n*24+r)*512 + tid]       = a0[r];
    F[(size_t)(n*24+r)*512 + tid + 256] = a1[r];
  }
  if (tid < 24){
    float s=0.f;
    for (int ss=0; ss<200; ss++) s += w6[tid*200+ss];
    S[n*24+tid]=s;
  }
}

__global__ __launch_bounds__(128) void kP3(const float* __restrict__ F,
                                           const float* __restrict__ WcvT,
                                           float* __restrict__ M){
  __shared__ float Fl[3072];
  int tid = threadIdx.x; int b = blockIdx.x; int n = b>>2, h = b&3;
  for (int e = tid; e < 3072; e += 128) Fl[e] = F[(size_t)(n*24 + h*6)*512 + e];
  __syncthreads();
  float acc[6];
#pragma unroll
  for (int i=0;i<6;i++) acc[i]=0.f;
  for (int k=0;k<512;k++){
    float w = WcvT[k*512 + h*128 + tid];
#pragma unroll
    for (int i=0;i<6;i++) acc[i] += w * Fl[i*512+k];
  }
#pragma unroll
  for (int i=0;i<6;i++) M[(size_t)(n*24+h*6+i)*128 + tid] = acc[i];
}

// ---------------- state init ----------------

// fills both xcat buffers' constant regions + zeros, zeros both hcat, zeros c,
// zeros the grid-barrier flags (one 128B line per block + gen line)
__global__ __launch_bounds__(512) void kinit(const float* __restrict__ ball,
                    const int* __restrict__ roles, const float* __restrict__ remb,
                    _Float16* __restrict__ x0, _Float16* __restrict__ x1,
                    _Float16* __restrict__ hc0, _Float16* __restrict__ hc1,
                    float* __restrict__ c0, float* __restrict__ c1,
                    unsigned* __restrict__ bar){
  int n = blockIdx.x, tid = threadIdx.x;
  int b = n/10;
  int role = roles[n];
  for (int c = tid; c < XC0; c += 512){
    float v = 0.f;
    if (c>=2 && c<4)       v = ball[b*2 + (c-2)];
    else if (c>=4 && c<36) v = remb[role*32 + (c-4)];
    _Float16 hv = (_Float16)v;
    x0[(size_t)n*XC0+c] = hv;
    x1[(size_t)n*XC0+c] = hv;
  }
  for (int c = tid; c < XC1; c += 512){
    hc0[(size_t)n*XC1+c] = (_Float16)0.f;
    hc1[(size_t)n*XC1+c] = (_Float16)0.f;
  }
  for (int e = tid; e < 512; e += 512){
    c0[n*512+e]=0.f; c1[n*512+e]=0.f;
  }
  if (tid < FL) bar[n*FL + tid] = 0u;                       // own flag line
  if (n == 0 && tid >= 128 && tid < 128+FL)
    bar[NBLK*FL + (tid-128)] = 0u;                          // gen line
}

// attention (Taylor-moment) for t=0 into xcat buf0
__global__ __launch_bounds__(128) void katt0(const float* __restrict__ ipos,
                                             const float* __restrict__ M,
                                             const float* __restrict__ S,
                                             const float* __restrict__ bv2,
                                             _Float16* __restrict__ x){
  int n = blockIdx.x, tid = threadIdx.x;
  float p0 = ipos[n*2], p1 = ipos[n*2+1];
  if (tid==0){ x[(size_t)n*XC0]=(_Float16)p0; x[(size_t)n*XC0+1]=(_Float16)p1; }
  float fa=p0*p0, fb=p0*p1, fc=p1*p1;
  for (int hd = tid; hd < 512; hd += 128){
    int h = hd>>7;
    int sb = n*24 + h*6;
    float den = S[sb] + p0*S[sb+1] + p1*S[sb+2] + fa*S[sb+3] + fb*S[sb+4] + fc*S[sb+5];
    const float* mp = M + (size_t)sb*128 + (hd&127);
    float num = mp[0] + p0*mp[128] + p1*mp[256] + fa*mp[384] + fb*mp[512] + fc*mp[640];
    x[(size_t)n*XC0 + 36 + hd] = (_Float16)(num/den + bv2[hd]);
  }
}

// ---------------- per-step bodies (shared by fallback + persistent) ----------

// One layer's full gate GEMM (K = lda cat width) + fused LSTM.
// 640 tasks = 20 mblk (32 rows) x 32 jb (16 cols/gate). 4 waves, 1 gate each.
// LDS double-buffered K=64 chunks; per buf: A 32x64 @0, B 64x64 @2048 halfs.
// Rows are 128B -> naive column reads are 16-way bank conflicts; both writes
// and reads use the XOR swizzle  halfs_off(row, slot) = row*64 + ((slot ^
// (row&7))<<3), slot = col/8.  (T2 / guide G4.)
__device__ __forceinline__ void gates_body(
    const _Float16* __restrict__ A, int lda, int nc,
    const _Float16* __restrict__ B,
    const float* __restrict__ bias, float* __restrict__ cst,
    _Float16* __restrict__ h1p, int ldh1, int co1,
    _Float16* __restrict__ h2p, int ldh2, int co2,
    int bx, _Float16* sbase, float (*eps)[32][16]){
  int tid = threadIdx.x, w = tid>>6, lane = tid&63;
  int lr = lane&15, lq = lane>>4;
  int mblk = bx>>5, jb = bx&31;
  int m0 = mblk*32, j0 = jb*16;
  int li = lane>>3, lc = lane&7;
  const _Float16* gA  = A + (size_t)(m0 + w*8 + li)*lda + lc*8;
  const _Float16* gB0 = B + (size_t)(w*512 + j0 + li)*lda + lc*8;
  const _Float16* gB1 = B + (size_t)(w*512 + j0 + 8 + li)*lda + lc*8;
  // swizzled LDS write offsets (row&7 == li for all three tiles)
  int sA  = (w*8 + li)*64        + ((lc ^ li)<<3);
  int sB0 = 2048 + (w*16 + li)*64 + ((lc ^ li)<<3);
  int sB1 = 2048 + (w*16 + 8 + li)*64 + ((lc ^ li)<<3);
  // swizzled LDS read offsets (A rows lr and 16+lr share row&7 = lr&7)
  int ra7 = lr & 7;
  int fA00 = lr*64        + (((lq  ) ^ ra7)<<3);
  int fA01 = lr*64        + (((lq+4) ^ ra7)<<3);
  int fA10 = (16+lr)*64   + (((lq  ) ^ ra7)<<3);
  int fA11 = (16+lr)*64   + (((lq+4) ^ ra7)<<3);
  int fB0  = 2048 + (w*16+lr)*64 + (((lq  ) ^ ra7)<<3);
  int fB1  = 2048 + (w*16+lr)*64 + (((lq+4) ^ ra7)<<3);
  hx8 rA  = *(const hx8*)(gA);
  hx8 rB0 = *(const hx8*)(gB0);
  hx8 rB1 = *(const hx8*)(gB1);
  fx4 ac0={0.f,0.f,0.f,0.f}, ac1={0.f,0.f,0.f,0.f};
  for (int c=0; c<nc; ++c){
    _Float16* sb = sbase + (c&1)*6144;
    *(hx8*)(sb + sA)  = rA;
    *(hx8*)(sb + sB0) = rB0;
    *(hx8*)(sb + sB1) = rB1;
    __syncthreads();
    if (c+1 < nc){
      int k = (c+1)*64;
      rA  = *(const hx8*)(gA  + k);
      rB0 = *(const hx8*)(gB0 + k);
      rB1 = *(const hx8*)(gB1 + k);
    }
    hx8 b0 = *(const hx8*)(sb + fB0);
    hx8 a0 = *(const hx8*)(sb + fA00);
    hx8 a1 = *(const hx8*)(sb + fA10);
    ac0 = __builtin_amdgcn_mfma_f32_16x16x32_f16(a0, b0, ac0, 0,0,0);
    ac1 = __builtin_amdgcn_mfma_f32_16x16x32_f16(a1, b0, ac1, 0,0,0);
    hx8 b1  = *(const hx8*)(sb + fB1);
    hx8 a0b = *(const hx8*)(sb + fA01);
    hx8 a1b = *(const hx8*)(sb + fA11);
    ac0 = __builtin_amdgcn_mfma_f32_16x16x32_f16(a0b, b1, ac0, 0,0,0);
    ac1 = __builtin_amdgcn_mfma_f32_16x16x32_f16(a1b, b1, ac1, 0,0,0);
  }
#pragma unroll
  for (int r=0;r<4;r++){
    eps[w][lq*4+r][lr]    = ac0[r];
    eps[w][16+lq*4+r][lr] = ac1[r];
  }
  __syncthreads();
#pragma unroll
  for (int e=0;e<2;e++){
    int idx = e*256 + tid;
    int ml = idx>>4, j = idx&15;
    float gi = eps[0][ml][j] + bias[       j0+j];
    float gf = eps[1][ml][j] + bias[ 512 + j0+j];
    float gg = eps[2][ml][j] + bias[1024 + j0+j];
    float go = eps[3][ml][j] + bias[1536 + j0+j];
    int ci = (m0+ml)*512 + j0 + j;
    float c_ = cst[ci];
    float cn = sigm(gf)*c_ + sigm(gi)*tanh_(gg);
    float hn = sigm(go)*tanh_(cn);
    cst[ci] = cn;
    _Float16 hh = (_Float16)hn;
    h1p[(size_t)(m0+ml)*ldh1 + co1 + j0 + j] = hh;
    if (h2p) h2p[(size_t)(m0+ml)*ldh2 + co2 + j0 + j] = hh;
  }
}

// fallback wrapper (identical behavior)
__global__ __launch_bounds__(256) void kgates(
    const _Float16* __restrict__ A, int lda, int nc,
    const _Float16* __restrict__ B,
    const float* __restrict__ bias, float* __restrict__ cst,
    _Float16* __restrict__ h1p, int ldh1, int co1,
    _Float16* __restrict__ h2p, int ldh2, int co2){
  __shared__ __align__(16) char smem[32768];
  gates_body(A, lda, nc, B, bias, cst, h1p, ldh1, co1, h2p, ldh2, co2,
             blockIdx.x, (_Float16*)smem, (float(*)[32][16])(smem + 24576));
}

// head + next-step attention, 256 threads, 16 seqs per call (n0 = base seq).
__device__ __forceinline__ void s3_body(const _Float16* __restrict__ h1, int ldh,
    const _Float16* __restrict__ Wf1, const float* __restrict__ bf1,
    const float* __restrict__ Wf2, const float* __restrict__ bf2,
    const float* __restrict__ M, const float* __restrict__ S,
    const float* __restrict__ bv2, _Float16* __restrict__ xn,
    float* __restrict__ out, int t, int n0,
    float (*hid)[264], float (*posL)[2], float (*denL)[4]){
  int tid = threadIdx.x, w = tid>>6, lane = tid&63;
  int lr = lane&15, lq = lane>>4;
  fx4 acc[4];
#pragma unroll
  for (int c=0;c<4;c++) acc[c] = (fx4){0.f,0.f,0.f,0.f};
  {
    const _Float16* ap = h1 + (size_t)(n0+lr)*ldh + lq*8;
    for (int ks=0; ks<16; ks++){
      hx8 a = *(const hx8*)(ap + ks*32);
#pragma unroll
      for (int c=0;c<4;c++){
        const _Float16* bp = Wf1 + (size_t)(w*64 + c*16 + lr)*512 + ks*32 + lq*8;
        acc[c] = __builtin_amdgcn_mfma_f32_16x16x32_f16(a, *(const hx8*)bp, acc[c], 0,0,0);
      }
    }
  }
#pragma unroll
  for (int c=0;c<4;c++)
#pragma unroll
    for (int r=0;r<4;r++){
      int col = w*64 + c*16 + lr;
      hid[lq*4+r][col] = fmaxf(acc[c][r] + bf1[col], 0.f);
    }
  __syncthreads();
  {
    int nn = tid>>4, o = (tid>>3)&1, sub = tid&7;
    float s = 0.f;
#pragma unroll
    for (int k2=0;k2<32;k2++) s += hid[nn][k2*8 + sub] * Wf2[o*256 + k2*8 + sub];
    s += __shfl_xor(s, 1, 64);
    s += __shfl_xor(s, 2, 64);
    s += __shfl_xor(s, 4, 64);
    if (sub==0){
      s += bf2[o];
      out[((size_t)(n0+nn)*TSTEPS + t)*2 + o] = s;
      posL[nn][o] = s;
      xn[(size_t)(n0+nn)*XC0 + o] = (_Float16)s;
    }
  }
  __syncthreads();
  if (tid < 64){
    int nn = tid>>2, h = tid&3;
    float p0 = posL[nn][0], p1 = posL[nn][1];
    int sb = (n0+nn)*24 + h*6;
    float den = S[sb] + p0*S[sb+1] + p1*S[sb+2] + p0*p0*S[sb+3] + p0*p1*S[sb+4] + p1*p1*S[sb+5];
    denL[nn][h] = 1.0f/den;
  }
  __syncthreads();
#pragma unroll
  for (int half=0; half<2; half++){
    int hd = half*256 + tid;
    int h = hd>>7, d = hd&127;
    for (int nn=0; nn<16; nn++){
      float p0 = posL[nn][0], p1 = posL[nn][1];
      float fa = p0*p0, fb = p0*p1, fc = p1*p1;
      const float* mp = M + (size_t)((n0+nn)*24 + h*6)*128 + d;
      float num = mp[0] + p0*mp[128] + p1*mp[256] + fa*mp[384] + fb*mp[512] + fc*mp[640];
      xn[(size_t)(n0+nn)*XC0 + 36 + hd] = (_Float16)(num*denL[nn][h] + bv2[hd]);
    }
  }
}

// fallback wrapper
__global__ __launch_bounds__(256) void ks3b(const _Float16* __restrict__ h1, int ldh,
    const _Float16* __restrict__ Wf1, const float* __restrict__ bf1,
    const float* __restrict__ Wf2, const float* __restrict__ bf2,
    const float* __restrict__ M, const float* __restrict__ S,
    const float* __restrict__ bv2, _Float16* __restrict__ xn,
    float* __restrict__ out, int t){
  __shared__ float hid[16][264];
  __shared__ float posL[16][2];
  __shared__ float denL[16][4];
  s3_body(h1, ldh, Wf1, bf1, Wf2, bf2, M, S, bv2, xn, out, t,
          blockIdx.x*16, hid, posL, denL);
}

// ---------------- persistent loop kernel ----------------

// Flag-array + master-scan grid barrier (monotone generation values, no
// counter RMWs, no reset pass):
//  * arrival:  block i release-stores val to its private 128B flag line
//  * detect:   block 0's 256 threads scan the 639 flags in parallel
//  * release:  block 0 release-stores val to gen; waiters acquire-spin on it
// Agent-scope ops keep XCD L2s coherent at the handoff (guide G16).
__device__ __forceinline__ void gbar(unsigned* bar, int bid, unsigned val){
  __syncthreads();
  unsigned* gen = bar + NBLK*FL;
  if (bid == 0){
    for (int i = 1 + (int)threadIdx.x; i < NBLK; i += 256){
      while (__hip_atomic_load(bar + (size_t)i*FL, __ATOMIC_RELAXED,
                               __HIP_MEMORY_SCOPE_AGENT) < val)
        __builtin_amdgcn_s_sleep(4);
    }
    __threadfence();          // acquire side: order flag observations
    __syncthreads();          // all master threads saw their subsets
    if (threadIdx.x == 0)
      __hip_atomic_store(gen, val, __ATOMIC_RELEASE, __HIP_MEMORY_SCOPE_AGENT);
  } else {
    if (threadIdx.x == 0){
      __hip_atomic_store(bar + (size_t)bid*FL, val, __ATOMIC_RELEASE,
                         __HIP_MEMORY_SCOPE_AGENT);
      while (__hip_atomic_load(gen, __ATOMIC_RELAXED,
                               __HIP_MEMORY_SCOPE_AGENT) < val)
        __builtin_amdgcn_s_sleep(4);
      (void)__hip_atomic_load(gen, __ATOMIC_ACQUIRE, __HIP_MEMORY_SCOPE_AGENT);
    }
  }
  __syncthreads();
}

struct LoopArgs {
  const _Float16* B0; const _Float16* B1;
  const float* b0; const float* b1;
  float* c0; float* c1;
  _Float16* x0; _Float16* x1; _Float16* h0; _Float16* h1;
  const _Float16* Wf1; const float* bf1; const float* Wf2; const float* bf2;
  const float* M; const float* S; const float* bv2;
  float* out; unsigned* bar;
};

// 640 blocks x 256 thr, 32KB LDS/block; min 3 blocks/CU co-resident (checked
// on host via occupancy query; fallback to multi-launch otherwise).
__global__ __launch_bounds__(256, 3) void kloop(LoopArgs a){
  __shared__ __align__(16) char smem[32768];
  _Float16* sbase = (_Float16*)smem;
  float (*eps)[32][16] = (float(*)[32][16])(smem + 24576);
  float (*hid)[264] = (float(*)[264])smem;
  float (*posL)[2] = (float(*)[2])(smem + 16896);
  float (*denL)[4] = (float(*)[4])(smem + 17024);
  int bid = blockIdx.x;
  for (int t = 0; t < TSTEPS; ++t){
    unsigned bb = (unsigned)(t*3);
    _Float16* xin = (t&1) ? a.x1 : a.x0;
    _Float16* xnx = (t&1) ? a.x0 : a.x1;
    _Float16* hin = (t&1) ? a.h1 : a.h0;
    _Float16* hnx = (t&1) ? a.h0 : a.h1;
    // layer 0: A=[x|h0] (K=1088) -> h0_t into hin[.,0:512] and xnx[.,576:1088]
    gates_body(xin, XC0, 17, a.B0, a.b0, a.c0, hin, XC1, 0, xnx, XC0, 576,
               bid, sbase, eps);
    gbar(a.bar, bid, bb+1);
    // layer 1: A=[h0|h1] (K=1024) -> h1_t into hnx[.,512:1024]
    gates_body(hin, XC1, 16, a.B1, a.b1, a.c1, hnx, XC1, 512,
               (_Float16*)0, 0, 0, bid, sbase, eps);
    gbar(a.bar, bid, bb+2);
    // head + attention for next x -> xnx[.,0:2], xnx[.,36:548]
    if (bid < 40)
      s3_body(hnx + 512, XC1, a.Wf1, a.bf1, a.Wf2, a.bf2, a.M, a.S, a.bv2,
              xnx, a.out, t, bid*16, hid, posL, denL);
    gbar(a.bar, bid, bb+3);
  }
}

// ---------------------------------------------------------------------------

extern "C" void kernel_launch(void* const* d_in, const int* in_sizes, int n_in,
                              void* d_out, int out_size, void* d_ws, size_t ws_size,
                              hipStream_t stream) {
  const float* ctx   = (const float*)d_in[0];
  const float* ipos  = (const float*)d_in[1];
  const float* ball  = (const float*)d_in[2];
  const int*   roles = (const int*)  d_in[3];
  const float* remb  = (const float*)d_in[5];
  const float* Wc    = (const float*)d_in[6];
  const float* bc    = (const float*)d_in[7];
  const float* Wq    = (const float*)d_in[8];
  const float* bq    = (const float*)d_in[9];
  const float* Wk    = (const float*)d_in[10];
  const float* bk    = (const float*)d_in[11];
  const float* Wv    = (const float*)d_in[12];
  const float* bv    = (const float*)d_in[13];
  const float* Wo    = (const float*)d_in[14];
  const float* bo    = (const float*)d_in[15];
  const float* Wih0  = (const float*)d_in[16];
  const float* Whh0  = (const float*)d_in[17];
  const float* bih0  = (const float*)d_in[18];
  const float* bhh0  = (const float*)d_in[19];
  const float* Wih1  = (const float*)d_in[20];
  const float* Whh1  = (const float*)d_in[21];
  const float* bih1  = (const float*)d_in[22];
  const float* bhh1  = (const float*)d_in[23];
  const float* Wf1   = (const float*)d_in[24];
  const float* bf1   = (const float*)d_in[25];
  const float* Wf2   = (const float*)d_in[26];
  const float* bf2   = (const float*)d_in[27];
  float* out = (float*)d_out;

  char* w = (char*)d_ws;
  auto alloc = [&](size_t bytes){ void* p = (void*)w; w += (bytes + 255) & ~(size_t)255; return p; };
  float* fY    = (float*)alloc(12*512*4);
  float* fcc   = (float*)alloc(12*4);
  float* fu    = (float*)alloc(3*512*4);
  float* fz    = (float*)alloc(12*512*4);
  float* fbv2  = (float*)alloc(512*4);
  float* fWcv  = (float*)alloc((size_t)512*512*4);
  float* fWcvT = (float*)alloc((size_t)512*512*4);
  float* fWmix = (float*)alloc((size_t)2048*512*4);
  _Float16* hB0  = (_Float16*)alloc((size_t)2048*XC0*2);
  _Float16* hB1  = (_Float16*)alloc((size_t)2048*XC1*2);
  _Float16* hWf1 = (_Float16*)alloc((size_t)256*512*2);
  float* fb0 = (float*)alloc(2048*4);
  float* fb1 = (float*)alloc(2048*4);
  float* fW6 = (float*)alloc((size_t)NSEQ*24*200*4);
  float* fS  = (float*)alloc((size_t)NSEQ*24*4);
  float* fF  = (float*)alloc((size_t)NSEQ*24*512*4);
  float* fM  = (float*)alloc((size_t)NSEQ*24*128*4);
  _Float16* xc0 = (_Float16*)alloc((size_t)NSEQ*XC0*2);
  _Float16* xc1 = (_Float16*)alloc((size_t)NSEQ*XC0*2);
  _Float16* hc0 = (_Float16*)alloc((size_t)NSEQ*XC1*2);
  _Float16* hc1 = (_Float16*)alloc((size_t)NSEQ*XC1*2);
  float* fc0 = (float*)alloc((size_t)NSEQ*512*4);
  float* fc1 = (float*)alloc((size_t)NSEQ*512*4);
  unsigned* bar = (unsigned*)alloc((size_t)(NBLK+1)*FL*4);

  // ---- folds ----
  kF1 <<<2,  256, 0, stream>>>(Wq, Wc, bc, bq, fu);
  kF2a<<<12, 512, 0, stream>>>(Wk, fu, fz);
  kF2b<<<12, 512, 0, stream>>>(fz, Wc, bc, bk, fu, fY, fcc);
  kFbv<<<2,  256, 0, stream>>>(Wv, bc, bv, fbv2);
  kgemm<<<dim3(8,8),  256, 0, stream>>>(Wv,   512, 0,  Wc, 512, fWcv,  512, 512);
  ktransp<<<1024, 256, 0, stream>>>(fWcv, fWcvT);
  kgemm<<<dim3(8,32), 256, 0, stream>>>(Wih0, 548, 36, Wo, 512, fWmix, 512, 512);
  kbcat0<<<2048, 256, 0, stream>>>(Wih0, fWmix, Whh0, hB0);
  kbcat1<<<2048, 256, 0, stream>>>(Wih1, Whh1, hB1);
  kcast<<<512,  256, 0, stream>>>(Wf1, hWf1, 256*512);
  kbias<<<8, 256, 0, stream>>>(Wih0, bo, bih0, bhh0, bih1, bhh1, fb0, fb1);

  // ---- moments ----
  kP1<<<NSEQ, 256, 0, stream>>>(ctx, fY, fcc, fW6);
  kP2<<<NSEQ, 256, 0, stream>>>(ctx, fW6, fF, fS);
  kP3<<<NSEQ*4, 128, 0, stream>>>(fF, fWcvT, fM);

  // ---- state init ----
  kinit<<<NSEQ, 512, 0, stream>>>(ball, roles, remb, xc0, xc1, hc0, hc1, fc0, fc1, bar);
  katt0<<<NSEQ, 128, 0, stream>>>(ipos, fM, fS, fbv2, xc0);

  // ---- recurrent loop: persistent kernel if co-residency is provable ----
  int maxb = 0;
  hipError_t qe = hipOccupancyMaxActiveBlocksPerMultiprocessor(
      &maxb, reinterpret_cast<const void*>(kloop), 256, 0);
  if (qe == hipSuccess && maxb >= 3){
    LoopArgs la;
    la.B0 = hB0; la.B1 = hB1; la.b0 = fb0; la.b1 = fb1;
    la.c0 = fc0; la.c1 = fc1;
    la.x0 = xc0; la.x1 = xc1; la.h0 = hc0; la.h1 = hc1;
    la.Wf1 = hWf1; la.bf1 = bf1; la.Wf2 = Wf2; la.bf2 = bf2;
    la.M = fM; la.S = fS; la.bv2 = fbv2; la.out = out; la.bar = bar;
    kloop<<<NBLK, 256, 0, stream>>>(la);
  } else {
    for (int t = 0; t < TSTEPS; ++t){
      _Float16* xin  = (t&1) ? xc1 : xc0;
      _Float16* xnx  = (t&1) ? xc0 : xc1;
      _Float16* hin  = (t&1) ? hc1 : hc0;
      _Float16* hnx  = (t&1) ? hc0 : hc1;
      kgates<<<640, 256, 0, stream>>>(xin, XC0, 17, hB0, fb0, fc0,
                                      hin, XC1, 0, xnx, XC0, 576);
      kgates<<<640, 256, 0, stream>>>(hin, XC1, 16, hB1, fb1, fc1,
                                      hnx, XC1, 512, (_Float16*)nullptr, 0, 0);
      ks3b<<<40, 256, 0, stream>>>(hnx + 512, XC1, hWf1, bf1, Wf2, bf2,
                                   fM, fS, fbv2, xnx, out, t);
    }
  }
}